// Round 3
// baseline (310.268 us; speedup 1.0000x reference)
//
#include <hip/hip_runtime.h>

// Problem constants
#define DIMC 256
#define BSZ  32
#define MDIM 2048
#define NDIM 2048

#define KVP_STRIDE ((size_t)BSZ * DIMC * DIMC)  // one split-K partial, in shorts

typedef __attribute__((ext_vector_type(8))) short bf16x8;   // 8 bf16 (4 VGPRs)
typedef __attribute__((ext_vector_type(4))) float f32x4;    // MFMA acc

static __device__ __forceinline__ unsigned short f2bf(float x) {
  unsigned int u = __float_as_uint(x);
  u += 0x7fffu + ((u >> 16) & 1u);          // round-to-nearest-even
  return (unsigned short)(u >> 16);
}
static __device__ __forceinline__ float bf2f(unsigned short h) {
  return __uint_as_float(((unsigned int)h) << 16);
}
// HW packed fp32->bf16 (RNE): low short = lo, high short = hi.
static __device__ __forceinline__ unsigned int cvt_pk_bf16(float lo, float hi) {
  unsigned int r;
  asm("v_cvt_pk_bf16_f32 %0, %1, %2" : "=v"(r) : "v"(lo), "v"(hi));
  return r;
}

// ---------------------------------------------------------------------------
// prep: Wt[e][c] = bf16(W[c][e]) ; zero rowsum
// ---------------------------------------------------------------------------
__global__ __launch_bounds__(256) void prep_kernel(
    const float* __restrict__ W, unsigned short* __restrict__ Wt,
    float* __restrict__ rowsum) {
  const int e = blockIdx.x, c = threadIdx.x;
  Wt[e * 256 + c] = f2bf(W[c * 256 + e]);
  if (e < 32) rowsum[e * 256 + c] = 0.f;
}

// ---------------------------------------------------------------------------
// phi_q[b][m][e] = relu(sum_c query[b][c][m] * Wt[e][c]) / 16   bf16, e-contig
// 128(m) x 128(e) tile, BK=32, software-pipelined staging (reg prefetch).
// ---------------------------------------------------------------------------
__global__ __launch_bounds__(256, 4) void phiq_kernel(
    const float* __restrict__ query, const unsigned short* __restrict__ Wt,
    unsigned short* __restrict__ phi_q) {
  __shared__ unsigned short As[128 * 40];  // [m][c], stride 40 bf16 = 80 B
  __shared__ unsigned short Bs[128 * 40];  // [e][c]
  const int b = blockIdx.z;
  const int m0 = blockIdx.x * 128;
  const int e0 = blockIdx.y * 128;
  const int t = threadIdx.x;
  const int lane = t & 63, wave = t >> 6;
  const int wr = wave >> 1, wc = wave & 1;
  const int q = lane >> 4, l15 = lane & 15;
  const float* qb = query + (size_t)b * DIMC * MDIM;
  f32x4 acc[4][4];
#pragma unroll
  for (int i = 0; i < 4; ++i)
#pragma unroll
    for (int j = 0; j < 4; ++j) acc[i][j] = (f32x4){0.f, 0.f, 0.f, 0.f};

  const int brow = t >> 2, bc8 = (t & 3) << 3;
  const int midx = t & 127, ch = (t >> 7) << 4;
  const float* src0 = qb + (size_t)ch * MDIM + m0 + midx;
  const unsigned short* wt0 = Wt + (size_t)(e0 + brow) * 256 + bc8;
  const unsigned short* wt1 = Wt + (size_t)(e0 + brow + 64) * 256 + bc8;

  // prologue: prefetch k0 = 0
  float v[16];
#pragma unroll
  for (int i = 0; i < 16; ++i) v[i] = src0[(size_t)i * MDIM];
  uint4 w0 = *(const uint4*)wt0;
  uint4 w1 = *(const uint4*)wt1;

  for (int it = 0; it < 8; ++it) {
    const int k0 = it * 32;
    // commit staged registers to LDS
    {
      unsigned int wpk[8];
#pragma unroll
      for (int i = 0; i < 8; ++i) wpk[i] = cvt_pk_bf16(v[2 * i], v[2 * i + 1]);
      *(uint4*)&As[midx * 40 + ch] = *(const uint4*)&wpk[0];
      *(uint4*)&As[midx * 40 + ch + 8] = *(const uint4*)&wpk[4];
      *(uint4*)&Bs[brow * 40 + bc8] = w0;
      *(uint4*)&Bs[(brow + 64) * 40 + bc8] = w1;
    }
    __syncthreads();
    // prefetch next k-step while MFMA runs
    if (it < 7) {
      const float* src = src0 + (size_t)(k0 + 32) * MDIM;
#pragma unroll
      for (int i = 0; i < 16; ++i) v[i] = src[(size_t)i * MDIM];
      w0 = *(const uint4*)(wt0 + k0 + 32);
      w1 = *(const uint4*)(wt1 + k0 + 32);
    }
    bf16x8 a[4], bv[4];
#pragma unroll
    for (int i = 0; i < 4; ++i)
      a[i] = *(const bf16x8*)&As[(wr * 64 + i * 16 + l15) * 40 + q * 8];
#pragma unroll
    for (int j = 0; j < 4; ++j)
      bv[j] = *(const bf16x8*)&Bs[(wc * 64 + j * 16 + l15) * 40 + q * 8];
#pragma unroll
    for (int i = 0; i < 4; ++i)
#pragma unroll
      for (int j = 0; j < 4; ++j)
        acc[i][j] =
            __builtin_amdgcn_mfma_f32_16x16x32_bf16(a[i], bv[j], acc[i][j], 0, 0, 0);
    __syncthreads();
  }
  unsigned short* dst = phi_q + (size_t)b * MDIM * DIMC;
#pragma unroll
  for (int i = 0; i < 4; ++i)
#pragma unroll
    for (int j = 0; j < 4; ++j) {
      const int e = e0 + wc * 64 + j * 16 + l15;
#pragma unroll
      for (int r = 0; r < 4; ++r) {
        const int m = m0 + wr * 64 + i * 16 + q * 4 + r;
        float vv = acc[i][j][r];
        vv = vv > 0.f ? vv * 0.0625f : 0.f;
        dst[(size_t)m * DIMC + e] = f2bf(vv);
      }
    }
}

// ---------------------------------------------------------------------------
// phi_k[b][e][n] = relu(sum_c Wt[e][c] * key[b][c][n])   bf16 out, n-contig
// + fused rowsum[b][e] += sum_n phi_k.  Software-pipelined staging.
// ---------------------------------------------------------------------------
__global__ __launch_bounds__(256, 4) void phik_kernel(
    const float* __restrict__ key, const unsigned short* __restrict__ Wt,
    unsigned short* __restrict__ phi_k, float* __restrict__ rowsum) {
  __shared__ unsigned short As[128 * 40];  // [e][c]
  __shared__ unsigned short Bs[128 * 40];  // [n][c]
  const int b = blockIdx.z;
  const int n0 = blockIdx.x * 128;
  const int e0 = blockIdx.y * 128;
  const int t = threadIdx.x;
  const int lane = t & 63, wave = t >> 6;
  const int wr = wave >> 1, wc = wave & 1;
  const int q = lane >> 4, l15 = lane & 15;
  const float* keyb = key + (size_t)b * DIMC * NDIM;
  f32x4 acc[4][4];
#pragma unroll
  for (int i = 0; i < 4; ++i)
#pragma unroll
    for (int j = 0; j < 4; ++j) acc[i][j] = (f32x4){0.f, 0.f, 0.f, 0.f};

  const int arow = t >> 2, ac8 = (t & 3) << 3;
  const int nidx = t & 127, ch = (t >> 7) << 4;
  const float* src0 = keyb + (size_t)ch * NDIM + n0 + nidx;
  const unsigned short* wt0 = Wt + (size_t)(e0 + arow) * 256 + ac8;
  const unsigned short* wt1 = Wt + (size_t)(e0 + arow + 64) * 256 + ac8;

  float v[16];
#pragma unroll
  for (int i = 0; i < 16; ++i) v[i] = src0[(size_t)i * NDIM];
  uint4 w0 = *(const uint4*)wt0;
  uint4 w1 = *(const uint4*)wt1;

  for (int it = 0; it < 8; ++it) {
    const int k0 = it * 32;
    {
      unsigned int wpk[8];
#pragma unroll
      for (int i = 0; i < 8; ++i) wpk[i] = cvt_pk_bf16(v[2 * i], v[2 * i + 1]);
      *(uint4*)&Bs[nidx * 40 + ch] = *(const uint4*)&wpk[0];
      *(uint4*)&Bs[nidx * 40 + ch + 8] = *(const uint4*)&wpk[4];
      *(uint4*)&As[arow * 40 + ac8] = w0;
      *(uint4*)&As[(arow + 64) * 40 + ac8] = w1;
    }
    __syncthreads();
    if (it < 7) {
      const float* src = src0 + (size_t)(k0 + 32) * NDIM;
#pragma unroll
      for (int i = 0; i < 16; ++i) v[i] = src[(size_t)i * NDIM];
      w0 = *(const uint4*)(wt0 + k0 + 32);
      w1 = *(const uint4*)(wt1 + k0 + 32);
    }
    bf16x8 a[4], bv[4];
#pragma unroll
    for (int i = 0; i < 4; ++i)
      a[i] = *(const bf16x8*)&As[(wr * 64 + i * 16 + l15) * 40 + q * 8];
#pragma unroll
    for (int j = 0; j < 4; ++j)
      bv[j] = *(const bf16x8*)&Bs[(wc * 64 + j * 16 + l15) * 40 + q * 8];
#pragma unroll
    for (int i = 0; i < 4; ++i)
#pragma unroll
      for (int j = 0; j < 4; ++j)
        acc[i][j] =
            __builtin_amdgcn_mfma_f32_16x16x32_bf16(a[i], bv[j], acc[i][j], 0, 0, 0);
    __syncthreads();
  }
  unsigned short* dst = phi_k + (size_t)b * DIMC * NDIM;
#pragma unroll
  for (int i = 0; i < 4; ++i)
#pragma unroll
    for (int r = 0; r < 4; ++r) {
      const int e = e0 + wr * 64 + i * 16 + q * 4 + r;
      float s = 0.f;
#pragma unroll
      for (int j = 0; j < 4; ++j) {
        float vv = acc[i][j][r];
        vv = vv > 0.f ? vv : 0.f;
        const int n = n0 + wc * 64 + j * 16 + l15;
        dst[(size_t)e * NDIM + n] = f2bf(vv);
        s += vv;
      }
#pragma unroll
      for (int m = 1; m < 16; m <<= 1) s += __shfl_xor(s, m, 64);
      if (l15 == 0) atomicAdd(&rowsum[b * DIMC + e], s);
    }
}

// ---------------------------------------------------------------------------
// kv partials: kvp[ks][b][d][e] = sum_{n in ks-th chunk} value[b][d][n]*phi_k[b][e][n]
// runtime split-K (1/2/4/8), 128(d) x 128(e) tile, BK=64, bf16 partials.
// ---------------------------------------------------------------------------
__global__ __launch_bounds__(256) void kv_kernel(
    const float* __restrict__ value, const unsigned short* __restrict__ phi_k,
    unsigned short* __restrict__ kvp, int kshift) {
  __shared__ unsigned short As[128 * 72];  // [d][n], stride 72 bf16 = 144 B
  __shared__ unsigned short Bs[128 * 72];  // [e][n]
  const int b = blockIdx.z >> kshift, ks = blockIdx.z & ((1 << kshift) - 1);
  const int d0 = blockIdx.x * 128, e0 = blockIdx.y * 128;
  const int t = threadIdx.x;
  const int lane = t & 63, wave = t >> 6;
  const int wr = wave >> 1, wc = wave & 1;
  const int q = lane >> 4, l15 = lane & 15;
  f32x4 acc[4][4];
#pragma unroll
  for (int i = 0; i < 4; ++i)
#pragma unroll
    for (int j = 0; j < 4; ++j) acc[i][j] = (f32x4){0.f, 0.f, 0.f, 0.f};

  const int row = t >> 2;
  const int c4 = (t & 3) << 2;  // float col base
  const int c8 = (t & 3) << 3;  // short col base

  const float* asrc0 = value + ((size_t)b * DIMC + d0 + row) * NDIM;
  const float* asrc1 = asrc0 + (size_t)64 * NDIM;
  const unsigned short* bsrc0 = phi_k + ((size_t)b * DIMC + e0 + row) * NDIM;
  const unsigned short* bsrc1 = bsrc0 + (size_t)64 * NDIM;

  const int nchunk = NDIM >> kshift;
  const int nbeg = ks * nchunk;
  for (int n0 = nbeg; n0 < nbeg + nchunk; n0 += 64) {
    __syncthreads();
#pragma unroll
    for (int i = 0; i < 4; ++i) {
      float4 f0 = *(const float4*)(asrc0 + n0 + c4 + i * 16);
      float4 f1 = *(const float4*)(asrc1 + n0 + c4 + i * 16);
      uint2 w0, w1;
      w0.x = cvt_pk_bf16(f0.x, f0.y); w0.y = cvt_pk_bf16(f0.z, f0.w);
      w1.x = cvt_pk_bf16(f1.x, f1.y); w1.y = cvt_pk_bf16(f1.z, f1.w);
      *(uint2*)&As[row * 72 + c4 + i * 16] = w0;
      *(uint2*)&As[(row + 64) * 72 + c4 + i * 16] = w1;
    }
#pragma unroll
    for (int i = 0; i < 2; ++i) {
      uint4 p0 = *(const uint4*)(bsrc0 + n0 + c8 + i * 32);
      uint4 p1 = *(const uint4*)(bsrc1 + n0 + c8 + i * 32);
      *(uint4*)&Bs[row * 72 + c8 + i * 32] = p0;
      *(uint4*)&Bs[(row + 64) * 72 + c8 + i * 32] = p1;
    }
    __syncthreads();
#pragma unroll
    for (int kk = 0; kk < 64; kk += 32) {
      bf16x8 a[4], bv[4];
#pragma unroll
      for (int i = 0; i < 4; ++i)
        a[i] = *(const bf16x8*)&As[(wr * 64 + i * 16 + l15) * 72 + kk + q * 8];
#pragma unroll
      for (int j = 0; j < 4; ++j)
        bv[j] = *(const bf16x8*)&Bs[(wc * 64 + j * 16 + l15) * 72 + kk + q * 8];
#pragma unroll
      for (int i = 0; i < 4; ++i)
#pragma unroll
        for (int j = 0; j < 4; ++j)
          acc[i][j] = __builtin_amdgcn_mfma_f32_16x16x32_bf16(a[i], bv[j],
                                                              acc[i][j], 0, 0, 0);
    }
  }
  unsigned short* dst = kvp + (size_t)ks * KVP_STRIDE + (size_t)b * DIMC * DIMC;
#pragma unroll
  for (int i = 0; i < 4; ++i)
#pragma unroll
    for (int j = 0; j < 4; ++j) {
      const int e = e0 + wc * 64 + j * 16 + l15;
#pragma unroll
      for (int r = 0; r < 4; ++r) {
        const int d = d0 + wr * 64 + i * 16 + q * 4 + r;
        dst[(size_t)d * DIMC + e] = f2bf(acc[i][j][r]);
      }
    }
}

// ---------------------------------------------------------------------------
// kvred: kvp[0] = sum over KS bf16 partials (in place into partial 0)
// ---------------------------------------------------------------------------
__global__ __launch_bounds__(256) void kvred_kernel(
    unsigned short* __restrict__ kvp, int KS) {
  const size_t idx8 = ((size_t)blockIdx.x * 256 + threadIdx.x) * 8;
  float s[8];
#pragma unroll
  for (int j = 0; j < 8; ++j) s[j] = 0.f;
  for (int p = 0; p < KS; ++p) {
    uint4 v = *(const uint4*)(kvp + (size_t)p * KVP_STRIDE + idx8);
    const unsigned short* u = (const unsigned short*)&v;
#pragma unroll
    for (int j = 0; j < 8; ++j) s[j] += bf2f(u[j]);
  }
  unsigned int w[4];
#pragma unroll
  for (int j = 0; j < 4; ++j) w[j] = cvt_pk_bf16(s[2 * j], s[2 * j + 1]);
  *(uint4*)(kvp + idx8) = *(const uint4*)w;
}

// ---------------------------------------------------------------------------
// out[b][d][m] = scale[b][m] * sum_e kv[d][e] * phi_q[m][e]   fp32 out
// scale fused: running dot of phi_q rows with LDS-resident rowsum.
// Software-pipelined staging.
// ---------------------------------------------------------------------------
__global__ __launch_bounds__(256, 4) void out_kernel(
    const unsigned short* __restrict__ kv,
    const unsigned short* __restrict__ phi_q,
    const float* __restrict__ rowsum, float* __restrict__ out) {
  __shared__ unsigned short As[128 * 40];  // [d][e]
  __shared__ unsigned short Bs[128 * 40];  // [m][e]
  __shared__ float rs_lds[256];
  __shared__ float red[512];
  __shared__ float scl[128];
  const int b = blockIdx.z;
  const int m0 = blockIdx.x * 128;
  const int d0 = blockIdx.y * 128;
  const int t = threadIdx.x;
  const int lane = t & 63, wave = t >> 6;
  const int wr = wave >> 1, wc = wave & 1;
  const int q = lane >> 4, l15 = lane & 15;

  rs_lds[t] = rowsum[b * DIMC + t];

  f32x4 acc[4][4];
#pragma unroll
  for (int i = 0; i < 4; ++i)
#pragma unroll
    for (int j = 0; j < 4; ++j) acc[i][j] = (f32x4){0.f, 0.f, 0.f, 0.f};

  const int row = t >> 2, c8 = (t & 3) << 3;
  const unsigned short* a0 = kv + ((size_t)b * DIMC + d0 + row) * DIMC + c8;
  const unsigned short* a1 = a0 + (size_t)64 * DIMC;
  const unsigned short* bsrc0 = phi_q + ((size_t)b * MDIM + m0 + row) * DIMC + c8;
  const unsigned short* bsrc1 = bsrc0 + (size_t)64 * DIMC;
  float sA = 0.f, sB = 0.f;

  // prologue prefetch k0 = 0
  uint4 pa0 = *(const uint4*)a0;
  uint4 pa1 = *(const uint4*)a1;
  uint4 pq0 = *(const uint4*)bsrc0;
  uint4 pq1 = *(const uint4*)bsrc1;

  for (int it = 0; it < 8; ++it) {
    const int k0 = it * 32;
    {
      *(uint4*)&As[row * 40 + c8] = pa0;
      *(uint4*)&As[(row + 64) * 40 + c8] = pa1;
      *(uint4*)&Bs[row * 40 + c8] = pq0;
      *(uint4*)&Bs[(row + 64) * 40 + c8] = pq1;
      const unsigned short* u0 = (const unsigned short*)&pq0;
      const unsigned short* u1 = (const unsigned short*)&pq1;
#pragma unroll
      for (int j = 0; j < 8; ++j) {
        const float r = rs_lds[k0 + c8 + j];
        sA += bf2f(u0[j]) * r;
        sB += bf2f(u1[j]) * r;
      }
    }
    __syncthreads();
    if (it < 7) {
      pa0 = *(const uint4*)(a0 + k0 + 32);
      pa1 = *(const uint4*)(a1 + k0 + 32);
      pq0 = *(const uint4*)(bsrc0 + k0 + 32);
      pq1 = *(const uint4*)(bsrc1 + k0 + 32);
    }
    bf16x8 a[4], bv[4];
#pragma unroll
    for (int i = 0; i < 4; ++i)
      a[i] = *(const bf16x8*)&As[(wr * 64 + i * 16 + l15) * 40 + q * 8];
#pragma unroll
    for (int j = 0; j < 4; ++j)
      bv[j] = *(const bf16x8*)&Bs[(wc * 64 + j * 16 + l15) * 40 + q * 8];
#pragma unroll
    for (int i = 0; i < 4; ++i)
#pragma unroll
      for (int j = 0; j < 4; ++j)
        acc[i][j] =
            __builtin_amdgcn_mfma_f32_16x16x32_bf16(a[i], bv[j], acc[i][j], 0, 0, 0);
    __syncthreads();
  }
  // reduce the 4 per-row scale partials and invert
  red[row * 4 + (t & 3)] = sA;
  red[(row + 64) * 4 + (t & 3)] = sB;
  __syncthreads();
  if (t < 128) {
    float s = red[t * 4] + red[t * 4 + 1] + red[t * 4 + 2] + red[t * 4 + 3];
    scl[t] = 1.f / (s + 1e-8f);
  }
  __syncthreads();

  float* ob = out + (size_t)b * DIMC * MDIM;
#pragma unroll
  for (int j = 0; j < 4; ++j) {
    const int ml = wc * 64 + j * 16 + l15;
    const int m = m0 + ml;
    const float sc = scl[ml];
#pragma unroll
    for (int i = 0; i < 4; ++i) {
#pragma unroll
      for (int r = 0; r < 4; ++r) {
        const int d = d0 + wr * 64 + i * 16 + q * 4 + r;
        ob[(size_t)d * MDIM + m] = acc[i][j][r] * sc;
      }
    }
  }
}

extern "C" void kernel_launch(void* const* d_in, const int* in_sizes, int n_in,
                              void* d_out, int out_size, void* d_ws, size_t ws_size,
                              hipStream_t stream) {
  const float* query = (const float*)d_in[0];  // [B,256,M]
  const float* key   = (const float*)d_in[1];  // [B,256,N]
  const float* value = (const float*)d_in[2];  // [B,256,N]
  const float* W     = (const float*)d_in[3];  // [256,256]
  float* out = (float*)d_out;                  // [B,256,M]

  unsigned short* Wt    = (unsigned short*)d_ws;             // 256*256
  unsigned short* phi_q = Wt + 65536;                        // B*M*256 (m-major)
  unsigned short* phi_k = phi_q + (size_t)BSZ * MDIM * DIMC; // B*256*N (e-major)
  unsigned short* kvp   = phi_k + (size_t)BSZ * DIMC * NDIM; // KS * B*256*256 bf16

  // choose split-K factor to fit the workspace (8 -> 4 -> 2 -> 1)
  const size_t base_shorts =
      65536 + (size_t)BSZ * MDIM * DIMC + (size_t)BSZ * DIMC * NDIM;
  int KS = 8, kshift = 3;
  while (KS > 1 &&
         (base_shorts + (size_t)KS * KVP_STRIDE) * 2 + (size_t)BSZ * DIMC * 4 >
             ws_size) {
    KS >>= 1;
    kshift -= 1;
  }
  float* rowsum = (float*)(kvp + (size_t)KS * KVP_STRIDE);   // B*256

  hipLaunchKernelGGL(prep_kernel, dim3(256), dim3(256), 0, stream, W, Wt, rowsum);
  hipLaunchKernelGGL(phiq_kernel, dim3(MDIM / 128, DIMC / 128, BSZ), dim3(256),
                     0, stream, query, Wt, phi_q);
  hipLaunchKernelGGL(phik_kernel, dim3(NDIM / 128, DIMC / 128, BSZ), dim3(256),
                     0, stream, key, Wt, phi_k, rowsum);
  hipLaunchKernelGGL(kv_kernel, dim3(DIMC / 128, DIMC / 128, BSZ << kshift),
                     dim3(256), 0, stream, value, phi_k, kvp, kshift);
  if (KS > 1)
    hipLaunchKernelGGL(kvred_kernel, dim3(1024), dim3(256), 0, stream, kvp, KS);
  hipLaunchKernelGGL(out_kernel, dim3(MDIM / 128, DIMC / 128, BSZ), dim3(256),
                     0, stream, kvp, phi_q, rowsum, out);
}

// Round 4
// 294.661 us; speedup vs baseline: 1.0530x; 1.0530x over previous
//
#include <hip/hip_runtime.h>

// Problem constants
#define DIMC 256
#define BSZ  32
#define MDIM 2048
#define NDIM 2048

#define KVP_STRIDE ((size_t)BSZ * DIMC * DIMC)  // one split-K partial, in shorts

typedef __attribute__((ext_vector_type(8))) short bf16x8;   // 8 bf16 (4 VGPRs)
typedef __attribute__((ext_vector_type(4))) float f32x4;    // MFMA acc

static __device__ __forceinline__ unsigned short f2bf(float x) {
  unsigned int u = __float_as_uint(x);
  u += 0x7fffu + ((u >> 16) & 1u);          // round-to-nearest-even
  return (unsigned short)(u >> 16);
}
static __device__ __forceinline__ float bf2f(unsigned short h) {
  return __uint_as_float(((unsigned int)h) << 16);
}
// HW packed fp32->bf16 (RNE): low short = lo, high short = hi.
static __device__ __forceinline__ unsigned int cvt_pk_bf16(float lo, float hi) {
  unsigned int r;
  asm("v_cvt_pk_bf16_f32 %0, %1, %2" : "=v"(r) : "v"(lo), "v"(hi));
  return r;
}

// ---------------------------------------------------------------------------
// prep: Wt[e][c] = bf16(W[c][e]) ; zero rowsum
// ---------------------------------------------------------------------------
__global__ __launch_bounds__(256) void prep_kernel(
    const float* __restrict__ W, unsigned short* __restrict__ Wt,
    float* __restrict__ rowsum) {
  const int e = blockIdx.x, c = threadIdx.x;
  Wt[e * 256 + c] = f2bf(W[c * 256 + e]);
  if (e < 32) rowsum[e * 256 + c] = 0.f;
}

// ---------------------------------------------------------------------------
// phi_q[b][m][e] = relu(sum_c query[b][c][m] * Wt[e][c]) / 16   bf16, e-contig
// 128(m) x 128(e) tile, BK=32, software-pipelined staging (reg prefetch).
// NOTE: no min-waves pin — acc[4][4] f32x4 = 64 VGPRs; pinning to 4 waves/EU
// forced a 64-VGPR cap and scratch spills (round-3 counters).
// ---------------------------------------------------------------------------
__global__ __launch_bounds__(256) void phiq_kernel(
    const float* __restrict__ query, const unsigned short* __restrict__ Wt,
    unsigned short* __restrict__ phi_q) {
  __shared__ unsigned short As[128 * 40];  // [m][c], stride 40 bf16 = 80 B
  __shared__ unsigned short Bs[128 * 40];  // [e][c]
  const int b = blockIdx.z;
  const int m0 = blockIdx.x * 128;
  const int e0 = blockIdx.y * 128;
  const int t = threadIdx.x;
  const int lane = t & 63, wave = t >> 6;
  const int wr = wave >> 1, wc = wave & 1;
  const int q = lane >> 4, l15 = lane & 15;
  const float* qb = query + (size_t)b * DIMC * MDIM;
  f32x4 acc[4][4];
#pragma unroll
  for (int i = 0; i < 4; ++i)
#pragma unroll
    for (int j = 0; j < 4; ++j) acc[i][j] = (f32x4){0.f, 0.f, 0.f, 0.f};

  const int brow = t >> 2, bc8 = (t & 3) << 3;
  const int midx = t & 127, ch = (t >> 7) << 4;
  const float* src0 = qb + (size_t)ch * MDIM + m0 + midx;
  const unsigned short* wt0 = Wt + (size_t)(e0 + brow) * 256 + bc8;
  const unsigned short* wt1 = Wt + (size_t)(e0 + brow + 64) * 256 + bc8;

  // prologue: prefetch k0 = 0
  float v[16];
#pragma unroll
  for (int i = 0; i < 16; ++i) v[i] = src0[(size_t)i * MDIM];
  uint4 w0 = *(const uint4*)wt0;
  uint4 w1 = *(const uint4*)wt1;

  for (int it = 0; it < 8; ++it) {
    const int k0 = it * 32;
    // commit staged registers to LDS
    {
      unsigned int wpk[8];
#pragma unroll
      for (int i = 0; i < 8; ++i) wpk[i] = cvt_pk_bf16(v[2 * i], v[2 * i + 1]);
      *(uint4*)&As[midx * 40 + ch] = *(const uint4*)&wpk[0];
      *(uint4*)&As[midx * 40 + ch + 8] = *(const uint4*)&wpk[4];
      *(uint4*)&Bs[brow * 40 + bc8] = w0;
      *(uint4*)&Bs[(brow + 64) * 40 + bc8] = w1;
    }
    __syncthreads();
    // prefetch next k-step while MFMA runs
    if (it < 7) {
      const float* src = src0 + (size_t)(k0 + 32) * MDIM;
#pragma unroll
      for (int i = 0; i < 16; ++i) v[i] = src[(size_t)i * MDIM];
      w0 = *(const uint4*)(wt0 + k0 + 32);
      w1 = *(const uint4*)(wt1 + k0 + 32);
    }
    bf16x8 a[4], bv[4];
#pragma unroll
    for (int i = 0; i < 4; ++i)
      a[i] = *(const bf16x8*)&As[(wr * 64 + i * 16 + l15) * 40 + q * 8];
#pragma unroll
    for (int j = 0; j < 4; ++j)
      bv[j] = *(const bf16x8*)&Bs[(wc * 64 + j * 16 + l15) * 40 + q * 8];
#pragma unroll
    for (int i = 0; i < 4; ++i)
#pragma unroll
      for (int j = 0; j < 4; ++j)
        acc[i][j] =
            __builtin_amdgcn_mfma_f32_16x16x32_bf16(a[i], bv[j], acc[i][j], 0, 0, 0);
    __syncthreads();
  }
  unsigned short* dst = phi_q + (size_t)b * MDIM * DIMC;
#pragma unroll
  for (int i = 0; i < 4; ++i)
#pragma unroll
    for (int j = 0; j < 4; ++j) {
      const int e = e0 + wc * 64 + j * 16 + l15;
#pragma unroll
      for (int r = 0; r < 4; ++r) {
        const int m = m0 + wr * 64 + i * 16 + q * 4 + r;
        float vv = acc[i][j][r];
        vv = vv > 0.f ? vv * 0.0625f : 0.f;
        dst[(size_t)m * DIMC + e] = f2bf(vv);
      }
    }
}

// ---------------------------------------------------------------------------
// phi_k[b][e][n] = relu(sum_c Wt[e][c] * key[b][c][n])   bf16 out, n-contig
// + fused rowsum[b][e] += sum_n phi_k.  Software-pipelined staging.
// ---------------------------------------------------------------------------
__global__ __launch_bounds__(256) void phik_kernel(
    const float* __restrict__ key, const unsigned short* __restrict__ Wt,
    unsigned short* __restrict__ phi_k, float* __restrict__ rowsum) {
  __shared__ unsigned short As[128 * 40];  // [e][c]
  __shared__ unsigned short Bs[128 * 40];  // [n][c]
  const int b = blockIdx.z;
  const int n0 = blockIdx.x * 128;
  const int e0 = blockIdx.y * 128;
  const int t = threadIdx.x;
  const int lane = t & 63, wave = t >> 6;
  const int wr = wave >> 1, wc = wave & 1;
  const int q = lane >> 4, l15 = lane & 15;
  const float* keyb = key + (size_t)b * DIMC * NDIM;
  f32x4 acc[4][4];
#pragma unroll
  for (int i = 0; i < 4; ++i)
#pragma unroll
    for (int j = 0; j < 4; ++j) acc[i][j] = (f32x4){0.f, 0.f, 0.f, 0.f};

  const int arow = t >> 2, ac8 = (t & 3) << 3;
  const int nidx = t & 127, ch = (t >> 7) << 4;
  const float* src0 = keyb + (size_t)ch * NDIM + n0 + nidx;
  const unsigned short* wt0 = Wt + (size_t)(e0 + arow) * 256 + ac8;
  const unsigned short* wt1 = Wt + (size_t)(e0 + arow + 64) * 256 + ac8;

  float v[16];
#pragma unroll
  for (int i = 0; i < 16; ++i) v[i] = src0[(size_t)i * NDIM];
  uint4 w0 = *(const uint4*)wt0;
  uint4 w1 = *(const uint4*)wt1;

  for (int it = 0; it < 8; ++it) {
    const int k0 = it * 32;
    {
      unsigned int wpk[8];
#pragma unroll
      for (int i = 0; i < 8; ++i) wpk[i] = cvt_pk_bf16(v[2 * i], v[2 * i + 1]);
      *(uint4*)&Bs[nidx * 40 + ch] = *(const uint4*)&wpk[0];
      *(uint4*)&Bs[nidx * 40 + ch + 8] = *(const uint4*)&wpk[4];
      *(uint4*)&As[arow * 40 + ac8] = w0;
      *(uint4*)&As[(arow + 64) * 40 + ac8] = w1;
    }
    __syncthreads();
    if (it < 7) {
      const float* src = src0 + (size_t)(k0 + 32) * NDIM;
#pragma unroll
      for (int i = 0; i < 16; ++i) v[i] = src[(size_t)i * NDIM];
      w0 = *(const uint4*)(wt0 + k0 + 32);
      w1 = *(const uint4*)(wt1 + k0 + 32);
    }
    bf16x8 a[4], bv[4];
#pragma unroll
    for (int i = 0; i < 4; ++i)
      a[i] = *(const bf16x8*)&As[(wr * 64 + i * 16 + l15) * 40 + q * 8];
#pragma unroll
    for (int j = 0; j < 4; ++j)
      bv[j] = *(const bf16x8*)&Bs[(wc * 64 + j * 16 + l15) * 40 + q * 8];
#pragma unroll
    for (int i = 0; i < 4; ++i)
#pragma unroll
      for (int j = 0; j < 4; ++j)
        acc[i][j] =
            __builtin_amdgcn_mfma_f32_16x16x32_bf16(a[i], bv[j], acc[i][j], 0, 0, 0);
    __syncthreads();
  }
  unsigned short* dst = phi_k + (size_t)b * DIMC * NDIM;
#pragma unroll
  for (int i = 0; i < 4; ++i)
#pragma unroll
    for (int r = 0; r < 4; ++r) {
      const int e = e0 + wr * 64 + i * 16 + q * 4 + r;
      float s = 0.f;
#pragma unroll
      for (int j = 0; j < 4; ++j) {
        float vv = acc[i][j][r];
        vv = vv > 0.f ? vv : 0.f;
        const int n = n0 + wc * 64 + j * 16 + l15;
        dst[(size_t)e * NDIM + n] = f2bf(vv);
        s += vv;
      }
#pragma unroll
      for (int m = 1; m < 16; m <<= 1) s += __shfl_xor(s, m, 64);
      if (l15 == 0) atomicAdd(&rowsum[b * DIMC + e], s);
    }
}

// ---------------------------------------------------------------------------
// kv partials: kvp[ks][b][d][e] = sum_{n in ks-th chunk} value[b][d][n]*phi_k[b][e][n]
// runtime split-K (1/2/4/8), 128(d) x 128(e) tile, BK=64, bf16 partials.
// ---------------------------------------------------------------------------
__global__ __launch_bounds__(256) void kv_kernel(
    const float* __restrict__ value, const unsigned short* __restrict__ phi_k,
    unsigned short* __restrict__ kvp, int kshift) {
  __shared__ unsigned short As[128 * 72];  // [d][n], stride 72 bf16 = 144 B
  __shared__ unsigned short Bs[128 * 72];  // [e][n]
  const int b = blockIdx.z >> kshift, ks = blockIdx.z & ((1 << kshift) - 1);
  const int d0 = blockIdx.x * 128, e0 = blockIdx.y * 128;
  const int t = threadIdx.x;
  const int lane = t & 63, wave = t >> 6;
  const int wr = wave >> 1, wc = wave & 1;
  const int q = lane >> 4, l15 = lane & 15;
  f32x4 acc[4][4];
#pragma unroll
  for (int i = 0; i < 4; ++i)
#pragma unroll
    for (int j = 0; j < 4; ++j) acc[i][j] = (f32x4){0.f, 0.f, 0.f, 0.f};

  const int row = t >> 2;
  const int c4 = (t & 3) << 2;  // float col base
  const int c8 = (t & 3) << 3;  // short col base

  const float* asrc0 = value + ((size_t)b * DIMC + d0 + row) * NDIM;
  const float* asrc1 = asrc0 + (size_t)64 * NDIM;
  const unsigned short* bsrc0 = phi_k + ((size_t)b * DIMC + e0 + row) * NDIM;
  const unsigned short* bsrc1 = bsrc0 + (size_t)64 * NDIM;

  const int nchunk = NDIM >> kshift;
  const int nbeg = ks * nchunk;
  for (int n0 = nbeg; n0 < nbeg + nchunk; n0 += 64) {
    __syncthreads();
#pragma unroll
    for (int i = 0; i < 4; ++i) {
      float4 f0 = *(const float4*)(asrc0 + n0 + c4 + i * 16);
      float4 f1 = *(const float4*)(asrc1 + n0 + c4 + i * 16);
      uint2 w0, w1;
      w0.x = cvt_pk_bf16(f0.x, f0.y); w0.y = cvt_pk_bf16(f0.z, f0.w);
      w1.x = cvt_pk_bf16(f1.x, f1.y); w1.y = cvt_pk_bf16(f1.z, f1.w);
      *(uint2*)&As[row * 72 + c4 + i * 16] = w0;
      *(uint2*)&As[(row + 64) * 72 + c4 + i * 16] = w1;
    }
#pragma unroll
    for (int i = 0; i < 2; ++i) {
      uint4 p0 = *(const uint4*)(bsrc0 + n0 + c8 + i * 32);
      uint4 p1 = *(const uint4*)(bsrc1 + n0 + c8 + i * 32);
      *(uint4*)&Bs[row * 72 + c8 + i * 32] = p0;
      *(uint4*)&Bs[(row + 64) * 72 + c8 + i * 32] = p1;
    }
    __syncthreads();
#pragma unroll
    for (int kk = 0; kk < 64; kk += 32) {
      bf16x8 a[4], bv[4];
#pragma unroll
      for (int i = 0; i < 4; ++i)
        a[i] = *(const bf16x8*)&As[(wr * 64 + i * 16 + l15) * 72 + kk + q * 8];
#pragma unroll
      for (int j = 0; j < 4; ++j)
        bv[j] = *(const bf16x8*)&Bs[(wc * 64 + j * 16 + l15) * 72 + kk + q * 8];
#pragma unroll
      for (int i = 0; i < 4; ++i)
#pragma unroll
        for (int j = 0; j < 4; ++j)
          acc[i][j] = __builtin_amdgcn_mfma_f32_16x16x32_bf16(a[i], bv[j],
                                                              acc[i][j], 0, 0, 0);
    }
  }
  unsigned short* dst = kvp + (size_t)ks * KVP_STRIDE + (size_t)b * DIMC * DIMC;
#pragma unroll
  for (int i = 0; i < 4; ++i)
#pragma unroll
    for (int j = 0; j < 4; ++j) {
      const int e = e0 + wc * 64 + j * 16 + l15;
#pragma unroll
      for (int r = 0; r < 4; ++r) {
        const int d = d0 + wr * 64 + i * 16 + q * 4 + r;
        dst[(size_t)d * DIMC + e] = f2bf(acc[i][j][r]);
      }
    }
}

// ---------------------------------------------------------------------------
// kvred: kvp[0] = sum over KS bf16 partials (in place into partial 0)
// ---------------------------------------------------------------------------
__global__ __launch_bounds__(256) void kvred_kernel(
    unsigned short* __restrict__ kvp, int KS) {
  const size_t idx8 = ((size_t)blockIdx.x * 256 + threadIdx.x) * 8;
  float s[8];
#pragma unroll
  for (int j = 0; j < 8; ++j) s[j] = 0.f;
  for (int p = 0; p < KS; ++p) {
    uint4 v = *(const uint4*)(kvp + (size_t)p * KVP_STRIDE + idx8);
    const unsigned short* u = (const unsigned short*)&v;
#pragma unroll
    for (int j = 0; j < 8; ++j) s[j] += bf2f(u[j]);
  }
  unsigned int w[4];
#pragma unroll
  for (int j = 0; j < 4; ++j) w[j] = cvt_pk_bf16(s[2 * j], s[2 * j + 1]);
  *(uint4*)(kvp + idx8) = *(const uint4*)w;
}

// ---------------------------------------------------------------------------
// out[b][d][m] = scale[b][m] * sum_e kv[d][e] * phi_q[m][e]   fp32 out
// scale fused: running dot of phi_q rows with LDS-resident rowsum.
// Software-pipelined staging.  No min-waves pin (spill avoidance).
// ---------------------------------------------------------------------------
__global__ __launch_bounds__(256) void out_kernel(
    const unsigned short* __restrict__ kv,
    const unsigned short* __restrict__ phi_q,
    const float* __restrict__ rowsum, float* __restrict__ out) {
  __shared__ unsigned short As[128 * 40];  // [d][e]
  __shared__ unsigned short Bs[128 * 40];  // [m][e]
  __shared__ float rs_lds[256];
  __shared__ float red[512];
  __shared__ float scl[128];
  const int b = blockIdx.z;
  const int m0 = blockIdx.x * 128;
  const int d0 = blockIdx.y * 128;
  const int t = threadIdx.x;
  const int lane = t & 63, wave = t >> 6;
  const int wr = wave >> 1, wc = wave & 1;
  const int q = lane >> 4, l15 = lane & 15;

  rs_lds[t] = rowsum[b * DIMC + t];

  f32x4 acc[4][4];
#pragma unroll
  for (int i = 0; i < 4; ++i)
#pragma unroll
    for (int j = 0; j < 4; ++j) acc[i][j] = (f32x4){0.f, 0.f, 0.f, 0.f};

  const int row = t >> 2, c8 = (t & 3) << 3;
  const unsigned short* a0 = kv + ((size_t)b * DIMC + d0 + row) * DIMC + c8;
  const unsigned short* a1 = a0 + (size_t)64 * DIMC;
  const unsigned short* bsrc0 = phi_q + ((size_t)b * MDIM + m0 + row) * DIMC + c8;
  const unsigned short* bsrc1 = bsrc0 + (size_t)64 * DIMC;
  float sA = 0.f, sB = 0.f;

  // prologue prefetch k0 = 0
  uint4 pa0 = *(const uint4*)a0;
  uint4 pa1 = *(const uint4*)a1;
  uint4 pq0 = *(const uint4*)bsrc0;
  uint4 pq1 = *(const uint4*)bsrc1;

  for (int it = 0; it < 8; ++it) {
    const int k0 = it * 32;
    {
      *(uint4*)&As[row * 40 + c8] = pa0;
      *(uint4*)&As[(row + 64) * 40 + c8] = pa1;
      *(uint4*)&Bs[row * 40 + c8] = pq0;
      *(uint4*)&Bs[(row + 64) * 40 + c8] = pq1;
      const unsigned short* u0 = (const unsigned short*)&pq0;
      const unsigned short* u1 = (const unsigned short*)&pq1;
#pragma unroll
      for (int j = 0; j < 8; ++j) {
        const float r = rs_lds[k0 + c8 + j];
        sA += bf2f(u0[j]) * r;
        sB += bf2f(u1[j]) * r;
      }
    }
    __syncthreads();
    if (it < 7) {
      pa0 = *(const uint4*)(a0 + k0 + 32);
      pa1 = *(const uint4*)(a1 + k0 + 32);
      pq0 = *(const uint4*)(bsrc0 + k0 + 32);
      pq1 = *(const uint4*)(bsrc1 + k0 + 32);
    }
    bf16x8 a[4], bv[4];
#pragma unroll
    for (int i = 0; i < 4; ++i)
      a[i] = *(const bf16x8*)&As[(wr * 64 + i * 16 + l15) * 40 + q * 8];
#pragma unroll
    for (int j = 0; j < 4; ++j)
      bv[j] = *(const bf16x8*)&Bs[(wc * 64 + j * 16 + l15) * 40 + q * 8];
#pragma unroll
    for (int i = 0; i < 4; ++i)
#pragma unroll
      for (int j = 0; j < 4; ++j)
        acc[i][j] =
            __builtin_amdgcn_mfma_f32_16x16x32_bf16(a[i], bv[j], acc[i][j], 0, 0, 0);
    __syncthreads();
  }
  // reduce the 4 per-row scale partials and invert
  red[row * 4 + (t & 3)] = sA;
  red[(row + 64) * 4 + (t & 3)] = sB;
  __syncthreads();
  if (t < 128) {
    float s = red[t * 4] + red[t * 4 + 1] + red[t * 4 + 2] + red[t * 4 + 3];
    scl[t] = 1.f / (s + 1e-8f);
  }
  __syncthreads();

  float* ob = out + (size_t)b * DIMC * MDIM;
#pragma unroll
  for (int j = 0; j < 4; ++j) {
    const int ml = wc * 64 + j * 16 + l15;
    const int m = m0 + ml;
    const float sc = scl[ml];
#pragma unroll
    for (int i = 0; i < 4; ++i) {
#pragma unroll
      for (int r = 0; r < 4; ++r) {
        const int d = d0 + wr * 64 + i * 16 + q * 4 + r;
        ob[(size_t)d * MDIM + m] = acc[i][j][r] * sc;
      }
    }
  }
}

extern "C" void kernel_launch(void* const* d_in, const int* in_sizes, int n_in,
                              void* d_out, int out_size, void* d_ws, size_t ws_size,
                              hipStream_t stream) {
  const float* query = (const float*)d_in[0];  // [B,256,M]
  const float* key   = (const float*)d_in[1];  // [B,256,N]
  const float* value = (const float*)d_in[2];  // [B,256,N]
  const float* W     = (const float*)d_in[3];  // [256,256]
  float* out = (float*)d_out;                  // [B,256,M]

  unsigned short* Wt    = (unsigned short*)d_ws;             // 256*256
  unsigned short* phi_q = Wt + 65536;                        // B*M*256 (m-major)
  unsigned short* phi_k = phi_q + (size_t)BSZ * MDIM * DIMC; // B*256*N (e-major)
  unsigned short* kvp   = phi_k + (size_t)BSZ * DIMC * NDIM; // KS * B*256*256 bf16

  // choose split-K factor to fit the workspace (8 -> 4 -> 2 -> 1)
  const size_t base_shorts =
      65536 + (size_t)BSZ * MDIM * DIMC + (size_t)BSZ * DIMC * NDIM;
  int KS = 8, kshift = 3;
  while (KS > 1 &&
         (base_shorts + (size_t)KS * KVP_STRIDE) * 2 + (size_t)BSZ * DIMC * 4 >
             ws_size) {
    KS >>= 1;
    kshift -= 1;
  }
  float* rowsum = (float*)(kvp + (size_t)KS * KVP_STRIDE);   // B*256

  hipLaunchKernelGGL(prep_kernel, dim3(256), dim3(256), 0, stream, W, Wt, rowsum);
  hipLaunchKernelGGL(phiq_kernel, dim3(MDIM / 128, DIMC / 128, BSZ), dim3(256),
                     0, stream, query, Wt, phi_q);
  hipLaunchKernelGGL(phik_kernel, dim3(NDIM / 128, DIMC / 128, BSZ), dim3(256),
                     0, stream, key, Wt, phi_k, rowsum);
  hipLaunchKernelGGL(kv_kernel, dim3(DIMC / 128, DIMC / 128, BSZ << kshift),
                     dim3(256), 0, stream, value, phi_k, kvp, kshift);
  if (KS > 1)
    hipLaunchKernelGGL(kvred_kernel, dim3(1024), dim3(256), 0, stream, kvp, KS);
  hipLaunchKernelGGL(out_kernel, dim3(MDIM / 128, DIMC / 128, BSZ), dim3(256),
                     0, stream, kvp, phi_q, rowsum, out);
}

// Round 5
// 283.473 us; speedup vs baseline: 1.0945x; 1.0395x over previous
//
#include <hip/hip_runtime.h>

// Problem constants
#define DIMC 256
#define BSZ  32
#define MDIM 2048
#define NDIM 2048

#define KVP_STRIDE ((size_t)BSZ * DIMC * DIMC)  // one split-K partial, in shorts

typedef __attribute__((ext_vector_type(8))) short bf16x8;   // 8 bf16 (4 VGPRs)
typedef __attribute__((ext_vector_type(4))) float f32x4;    // MFMA acc

static __device__ __forceinline__ unsigned short f2bf(float x) {
  unsigned int u = __float_as_uint(x);
  u += 0x7fffu + ((u >> 16) & 1u);          // round-to-nearest-even
  return (unsigned short)(u >> 16);
}
static __device__ __forceinline__ float bf2f(unsigned short h) {
  return __uint_as_float(((unsigned int)h) << 16);
}
// HW packed fp32->bf16 (RNE): low short = lo, high short = hi.
static __device__ __forceinline__ unsigned int cvt_pk_bf16(float lo, float hi) {
  unsigned int r;
  asm("v_cvt_pk_bf16_f32 %0, %1, %2" : "=v"(r) : "v"(lo), "v"(hi));
  return r;
}

// ---------------------------------------------------------------------------
// prep: Wt[e][c] = bf16(W[c][e]) ; zero rowsum
// ---------------------------------------------------------------------------
__global__ __launch_bounds__(256) void prep_kernel(
    const float* __restrict__ W, unsigned short* __restrict__ Wt,
    float* __restrict__ rowsum) {
  const int e = blockIdx.x, c = threadIdx.x;
  Wt[e * 256 + c] = f2bf(W[c * 256 + e]);
  if (e < 32) rowsum[e * 256 + c] = 0.f;
}

// ---------------------------------------------------------------------------
// Merged feature-map kernel: for z<32 (key path) and z>=32 (query path).
//   P[e][x] = relu(sum_c Wt[e][c] * X[b][c][x]),  X = key or query
// key path:   phi_k[b][e][n] = P (n-contig) + rowsum[b][e] += sum_n P
// query path: phi_q[b][m][e] = P^T / 16 (e-contig, 8B vector stores)
// 128(e) x 128(x) tile, BK=32, 1-deep register prefetch.
// 2048 blocks -> ~6-8 blocks/CU: TLP covers the per-K-step vmcnt stall.
// ---------------------------------------------------------------------------
__global__ __launch_bounds__(256) void phi_kernel(
    const float* __restrict__ query, const float* __restrict__ key,
    const unsigned short* __restrict__ Wt,
    unsigned short* __restrict__ phi_q, unsigned short* __restrict__ phi_k,
    float* __restrict__ rowsum) {
  __shared__ unsigned short As[128 * 40];  // [e][c], stride 40 bf16 = 80 B
  __shared__ unsigned short Bs[128 * 40];  // [x][c]
  const int z = blockIdx.z;
  const bool isKey = z < BSZ;
  const int b = isKey ? z : z - BSZ;
  const int x0 = blockIdx.x * 128;
  const int e0 = blockIdx.y * 128;
  const int t = threadIdx.x;
  const int lane = t & 63, wave = t >> 6;
  const int wr = wave >> 1, wc = wave & 1;
  const int q = lane >> 4, l15 = lane & 15;
  const float* Xb =
      (isKey ? key : query) + (size_t)b * DIMC * NDIM;  // MDIM == NDIM
  f32x4 acc[4][4];
#pragma unroll
  for (int i = 0; i < 4; ++i)
#pragma unroll
    for (int j = 0; j < 4; ++j) acc[i][j] = (f32x4){0.f, 0.f, 0.f, 0.f};

  const int arow = t >> 2, ac8 = (t & 3) << 3;       // Wt staging coords
  const int xidx = t & 127, ch = (t >> 7) << 4;      // X staging coords
  const float* src0 = Xb + (size_t)ch * NDIM + x0 + xidx;
  const unsigned short* wt0 = Wt + (size_t)(e0 + arow) * 256 + ac8;
  const unsigned short* wt1 = Wt + (size_t)(e0 + arow + 64) * 256 + ac8;

  // prologue: prefetch k0 = 0
  float v[16];
#pragma unroll
  for (int i = 0; i < 16; ++i) v[i] = src0[(size_t)i * NDIM];
  uint4 w0 = *(const uint4*)wt0;
  uint4 w1 = *(const uint4*)wt1;

  for (int it = 0; it < 8; ++it) {
    const int k0 = it * 32;
    // commit staged registers to LDS
    {
      unsigned int wpk[8];
#pragma unroll
      for (int i = 0; i < 8; ++i) wpk[i] = cvt_pk_bf16(v[2 * i], v[2 * i + 1]);
      *(uint4*)&Bs[xidx * 40 + ch] = *(const uint4*)&wpk[0];
      *(uint4*)&Bs[xidx * 40 + ch + 8] = *(const uint4*)&wpk[4];
      *(uint4*)&As[arow * 40 + ac8] = w0;
      *(uint4*)&As[(arow + 64) * 40 + ac8] = w1;
    }
    __syncthreads();
    // prefetch next k-step while MFMA runs
    if (it < 7) {
      const float* src = src0 + (size_t)(k0 + 32) * NDIM;
#pragma unroll
      for (int i = 0; i < 16; ++i) v[i] = src[(size_t)i * NDIM];
      w0 = *(const uint4*)(wt0 + k0 + 32);
      w1 = *(const uint4*)(wt1 + k0 + 32);
    }
    bf16x8 a[4], bv[4];
#pragma unroll
    for (int i = 0; i < 4; ++i)
      a[i] = *(const bf16x8*)&As[(wr * 64 + i * 16 + l15) * 40 + q * 8];
#pragma unroll
    for (int j = 0; j < 4; ++j)
      bv[j] = *(const bf16x8*)&Bs[(wc * 64 + j * 16 + l15) * 40 + q * 8];
#pragma unroll
    for (int i = 0; i < 4; ++i)
#pragma unroll
      for (int j = 0; j < 4; ++j)
        acc[i][j] =
            __builtin_amdgcn_mfma_f32_16x16x32_bf16(a[i], bv[j], acc[i][j], 0, 0, 0);
    __syncthreads();
  }

  if (isKey) {
    // phi_k[b][e][n] n-contig + fused rowsum
    unsigned short* dst = phi_k + (size_t)b * DIMC * NDIM;
#pragma unroll
    for (int i = 0; i < 4; ++i)
#pragma unroll
      for (int r = 0; r < 4; ++r) {
        const int e = e0 + wr * 64 + i * 16 + q * 4 + r;
        float s = 0.f;
#pragma unroll
        for (int j = 0; j < 4; ++j) {
          float vv = acc[i][j][r];
          vv = vv > 0.f ? vv : 0.f;
          const int n = x0 + wc * 64 + j * 16 + l15;
          dst[(size_t)e * NDIM + n] = f2bf(vv);
          s += vv;
        }
#pragma unroll
        for (int m = 1; m < 16; m <<= 1) s += __shfl_xor(s, m, 64);
        if (l15 == 0) atomicAdd(&rowsum[b * DIMC + e], s);
      }
  } else {
    // phi_q[b][m][e] e-contig, 4 consecutive e per lane -> 8B stores
    unsigned short* dst = phi_q + (size_t)b * MDIM * DIMC;
#pragma unroll
    for (int i = 0; i < 4; ++i) {
      const int ebase = e0 + wr * 64 + i * 16 + q * 4;
#pragma unroll
      for (int j = 0; j < 4; ++j) {
        const int m = x0 + wc * 64 + j * 16 + l15;
        float r0 = acc[i][j][0], r1 = acc[i][j][1];
        float r2 = acc[i][j][2], r3 = acc[i][j][3];
        r0 = r0 > 0.f ? r0 * 0.0625f : 0.f;
        r1 = r1 > 0.f ? r1 * 0.0625f : 0.f;
        r2 = r2 > 0.f ? r2 * 0.0625f : 0.f;
        r3 = r3 > 0.f ? r3 * 0.0625f : 0.f;
        uint2 p;
        p.x = cvt_pk_bf16(r0, r1);
        p.y = cvt_pk_bf16(r2, r3);
        *(uint2*)&dst[(size_t)m * DIMC + ebase] = p;
      }
    }
  }
}

// ---------------------------------------------------------------------------
// kv partials: kvp[ks][b][d][e] = sum_{n in ks-th chunk} value[b][d][n]*phi_k[b][e][n]
// runtime split-K (1/2/4/8), 128(d) x 128(e) tile, BK=64, bf16 partials.
// ---------------------------------------------------------------------------
__global__ __launch_bounds__(256) void kv_kernel(
    const float* __restrict__ value, const unsigned short* __restrict__ phi_k,
    unsigned short* __restrict__ kvp, int kshift) {
  __shared__ unsigned short As[128 * 72];  // [d][n], stride 72 bf16 = 144 B
  __shared__ unsigned short Bs[128 * 72];  // [e][n]
  const int b = blockIdx.z >> kshift, ks = blockIdx.z & ((1 << kshift) - 1);
  const int d0 = blockIdx.x * 128, e0 = blockIdx.y * 128;
  const int t = threadIdx.x;
  const int lane = t & 63, wave = t >> 6;
  const int wr = wave >> 1, wc = wave & 1;
  const int q = lane >> 4, l15 = lane & 15;
  f32x4 acc[4][4];
#pragma unroll
  for (int i = 0; i < 4; ++i)
#pragma unroll
    for (int j = 0; j < 4; ++j) acc[i][j] = (f32x4){0.f, 0.f, 0.f, 0.f};

  const int row = t >> 2;
  const int c4 = (t & 3) << 2;  // float col base
  const int c8 = (t & 3) << 3;  // short col base

  const float* asrc0 = value + ((size_t)b * DIMC + d0 + row) * NDIM;
  const float* asrc1 = asrc0 + (size_t)64 * NDIM;
  const unsigned short* bsrc0 = phi_k + ((size_t)b * DIMC + e0 + row) * NDIM;
  const unsigned short* bsrc1 = bsrc0 + (size_t)64 * NDIM;

  const int nchunk = NDIM >> kshift;
  const int nbeg = ks * nchunk;
  for (int n0 = nbeg; n0 < nbeg + nchunk; n0 += 64) {
    __syncthreads();
#pragma unroll
    for (int i = 0; i < 4; ++i) {
      float4 f0 = *(const float4*)(asrc0 + n0 + c4 + i * 16);
      float4 f1 = *(const float4*)(asrc1 + n0 + c4 + i * 16);
      uint2 w0, w1;
      w0.x = cvt_pk_bf16(f0.x, f0.y); w0.y = cvt_pk_bf16(f0.z, f0.w);
      w1.x = cvt_pk_bf16(f1.x, f1.y); w1.y = cvt_pk_bf16(f1.z, f1.w);
      *(uint2*)&As[row * 72 + c4 + i * 16] = w0;
      *(uint2*)&As[(row + 64) * 72 + c4 + i * 16] = w1;
    }
#pragma unroll
    for (int i = 0; i < 2; ++i) {
      uint4 p0 = *(const uint4*)(bsrc0 + n0 + c8 + i * 32);
      uint4 p1 = *(const uint4*)(bsrc1 + n0 + c8 + i * 32);
      *(uint4*)&Bs[row * 72 + c8 + i * 32] = p0;
      *(uint4*)&Bs[(row + 64) * 72 + c8 + i * 32] = p1;
    }
    __syncthreads();
#pragma unroll
    for (int kk = 0; kk < 64; kk += 32) {
      bf16x8 a[4], bv[4];
#pragma unroll
      for (int i = 0; i < 4; ++i)
        a[i] = *(const bf16x8*)&As[(wr * 64 + i * 16 + l15) * 72 + kk + q * 8];
#pragma unroll
      for (int j = 0; j < 4; ++j)
        bv[j] = *(const bf16x8*)&Bs[(wc * 64 + j * 16 + l15) * 72 + kk + q * 8];
#pragma unroll
      for (int i = 0; i < 4; ++i)
#pragma unroll
        for (int j = 0; j < 4; ++j)
          acc[i][j] = __builtin_amdgcn_mfma_f32_16x16x32_bf16(a[i], bv[j],
                                                              acc[i][j], 0, 0, 0);
    }
  }
  unsigned short* dst = kvp + (size_t)ks * KVP_STRIDE + (size_t)b * DIMC * DIMC;
#pragma unroll
  for (int i = 0; i < 4; ++i)
#pragma unroll
    for (int j = 0; j < 4; ++j) {
      const int e = e0 + wc * 64 + j * 16 + l15;
#pragma unroll
      for (int r = 0; r < 4; ++r) {
        const int d = d0 + wr * 64 + i * 16 + q * 4 + r;
        dst[(size_t)d * DIMC + e] = f2bf(acc[i][j][r]);
      }
    }
}

// ---------------------------------------------------------------------------
// kvred: kvp[0] = sum over KS bf16 partials (in place into partial 0)
// ---------------------------------------------------------------------------
__global__ __launch_bounds__(256) void kvred_kernel(
    unsigned short* __restrict__ kvp, int KS) {
  const size_t idx8 = ((size_t)blockIdx.x * 256 + threadIdx.x) * 8;
  float s[8];
#pragma unroll
  for (int j = 0; j < 8; ++j) s[j] = 0.f;
  for (int p = 0; p < KS; ++p) {
    uint4 v = *(const uint4*)(kvp + (size_t)p * KVP_STRIDE + idx8);
    const unsigned short* u = (const unsigned short*)&v;
#pragma unroll
    for (int j = 0; j < 8; ++j) s[j] += bf2f(u[j]);
  }
  unsigned int w[4];
#pragma unroll
  for (int j = 0; j < 4; ++j) w[j] = cvt_pk_bf16(s[2 * j], s[2 * j + 1]);
  *(uint4*)(kvp + idx8) = *(const uint4*)w;
}

// ---------------------------------------------------------------------------
// out[b][d][m] = scale[b][m] * sum_e kv[d][e] * phi_q[m][e]   fp32 out
// scale fused: running dot of phi_q rows with LDS-resident rowsum.
// Software-pipelined staging.  No min-waves pin (spill avoidance).
// ---------------------------------------------------------------------------
__global__ __launch_bounds__(256) void out_kernel(
    const unsigned short* __restrict__ kv,
    const unsigned short* __restrict__ phi_q,
    const float* __restrict__ rowsum, float* __restrict__ out) {
  __shared__ unsigned short As[128 * 40];  // [d][e]
  __shared__ unsigned short Bs[128 * 40];  // [m][e]
  __shared__ float rs_lds[256];
  __shared__ float red[512];
  __shared__ float scl[128];
  const int b = blockIdx.z;
  const int m0 = blockIdx.x * 128;
  const int d0 = blockIdx.y * 128;
  const int t = threadIdx.x;
  const int lane = t & 63, wave = t >> 6;
  const int wr = wave >> 1, wc = wave & 1;
  const int q = lane >> 4, l15 = lane & 15;

  rs_lds[t] = rowsum[b * DIMC + t];

  f32x4 acc[4][4];
#pragma unroll
  for (int i = 0; i < 4; ++i)
#pragma unroll
    for (int j = 0; j < 4; ++j) acc[i][j] = (f32x4){0.f, 0.f, 0.f, 0.f};

  const int row = t >> 2, c8 = (t & 3) << 3;
  const unsigned short* a0 = kv + ((size_t)b * DIMC + d0 + row) * DIMC + c8;
  const unsigned short* a1 = a0 + (size_t)64 * DIMC;
  const unsigned short* bsrc0 = phi_q + ((size_t)b * MDIM + m0 + row) * DIMC + c8;
  const unsigned short* bsrc1 = bsrc0 + (size_t)64 * DIMC;
  float sA = 0.f, sB = 0.f;

  // prologue prefetch k0 = 0
  uint4 pa0 = *(const uint4*)a0;
  uint4 pa1 = *(const uint4*)a1;
  uint4 pq0 = *(const uint4*)bsrc0;
  uint4 pq1 = *(const uint4*)bsrc1;

  for (int it = 0; it < 8; ++it) {
    const int k0 = it * 32;
    {
      *(uint4*)&As[row * 40 + c8] = pa0;
      *(uint4*)&As[(row + 64) * 40 + c8] = pa1;
      *(uint4*)&Bs[row * 40 + c8] = pq0;
      *(uint4*)&Bs[(row + 64) * 40 + c8] = pq1;
      const unsigned short* u0 = (const unsigned short*)&pq0;
      const unsigned short* u1 = (const unsigned short*)&pq1;
#pragma unroll
      for (int j = 0; j < 8; ++j) {
        const float r = rs_lds[k0 + c8 + j];
        sA += bf2f(u0[j]) * r;
        sB += bf2f(u1[j]) * r;
      }
    }
    __syncthreads();
    if (it < 7) {
      pa0 = *(const uint4*)(a0 + k0 + 32);
      pa1 = *(const uint4*)(a1 + k0 + 32);
      pq0 = *(const uint4*)(bsrc0 + k0 + 32);
      pq1 = *(const uint4*)(bsrc1 + k0 + 32);
    }
    bf16x8 a[4], bv[4];
#pragma unroll
    for (int i = 0; i < 4; ++i)
      a[i] = *(const bf16x8*)&As[(wr * 64 + i * 16 + l15) * 40 + q * 8];
#pragma unroll
    for (int j = 0; j < 4; ++j)
      bv[j] = *(const bf16x8*)&Bs[(wc * 64 + j * 16 + l15) * 40 + q * 8];
#pragma unroll
    for (int i = 0; i < 4; ++i)
#pragma unroll
      for (int j = 0; j < 4; ++j)
        acc[i][j] =
            __builtin_amdgcn_mfma_f32_16x16x32_bf16(a[i], bv[j], acc[i][j], 0, 0, 0);
    __syncthreads();
  }
  // reduce the 4 per-row scale partials and invert
  red[row * 4 + (t & 3)] = sA;
  red[(row + 64) * 4 + (t & 3)] = sB;
  __syncthreads();
  if (t < 128) {
    float s = red[t * 4] + red[t * 4 + 1] + red[t * 4 + 2] + red[t * 4 + 3];
    scl[t] = 1.f / (s + 1e-8f);
  }
  __syncthreads();

  float* ob = out + (size_t)b * DIMC * MDIM;
#pragma unroll
  for (int j = 0; j < 4; ++j) {
    const int ml = wc * 64 + j * 16 + l15;
    const int m = m0 + ml;
    const float sc = scl[ml];
#pragma unroll
    for (int i = 0; i < 4; ++i) {
#pragma unroll
      for (int r = 0; r < 4; ++r) {
        const int d = d0 + wr * 64 + i * 16 + q * 4 + r;
        ob[(size_t)d * MDIM + m] = acc[i][j][r] * sc;
      }
    }
  }
}

extern "C" void kernel_launch(void* const* d_in, const int* in_sizes, int n_in,
                              void* d_out, int out_size, void* d_ws, size_t ws_size,
                              hipStream_t stream) {
  const float* query = (const float*)d_in[0];  // [B,256,M]
  const float* key   = (const float*)d_in[1];  // [B,256,N]
  const float* value = (const float*)d_in[2];  // [B,256,N]
  const float* W     = (const float*)d_in[3];  // [256,256]
  float* out = (float*)d_out;                  // [B,256,M]

  unsigned short* Wt    = (unsigned short*)d_ws;             // 256*256
  unsigned short* phi_q = Wt + 65536;                        // B*M*256 (m-major)
  unsigned short* phi_k = phi_q + (size_t)BSZ * MDIM * DIMC; // B*256*N (e-major)
  unsigned short* kvp   = phi_k + (size_t)BSZ * DIMC * NDIM; // KS * B*256*256 bf16

  // choose split-K factor to fit the workspace (8 -> 4 -> 2 -> 1)
  const size_t base_shorts =
      65536 + (size_t)BSZ * MDIM * DIMC + (size_t)BSZ * DIMC * NDIM;
  int KS = 8, kshift = 3;
  while (KS > 1 &&
         (base_shorts + (size_t)KS * KVP_STRIDE) * 2 + (size_t)BSZ * DIMC * 4 >
             ws_size) {
    KS >>= 1;
    kshift -= 1;
  }
  float* rowsum = (float*)(kvp + (size_t)KS * KVP_STRIDE);   // B*256

  hipLaunchKernelGGL(prep_kernel, dim3(256), dim3(256), 0, stream, W, Wt, rowsum);
  hipLaunchKernelGGL(phi_kernel, dim3(MDIM / 128, DIMC / 128, BSZ * 2),
                     dim3(256), 0, stream, query, key, Wt, phi_q, phi_k, rowsum);
  hipLaunchKernelGGL(kv_kernel, dim3(DIMC / 128, DIMC / 128, BSZ << kshift),
                     dim3(256), 0, stream, value, phi_k, kvp, kshift);
  if (KS > 1)
    hipLaunchKernelGGL(kvred_kernel, dim3(1024), dim3(256), 0, stream, kvp, KS);
  hipLaunchKernelGGL(out_kernel, dim3(MDIM / 128, DIMC / 128, BSZ), dim3(256),
                     0, stream, kvp, phi_q, rowsum, out);
}

// Round 6
// 278.039 us; speedup vs baseline: 1.1159x; 1.0195x over previous
//
#include <hip/hip_runtime.h>

// Problem constants
#define DIMC 256
#define BSZ  32
#define MDIM 2048
#define NDIM 2048

#define KVP_STRIDE ((size_t)BSZ * DIMC * DIMC)  // one split-K partial, in shorts

typedef __attribute__((ext_vector_type(8))) short bf16x8;   // 8 bf16 (4 VGPRs)
typedef __attribute__((ext_vector_type(4))) float f32x4;    // MFMA acc

static __device__ __forceinline__ unsigned short f2bf(float x) {
  unsigned int u = __float_as_uint(x);
  u += 0x7fffu + ((u >> 16) & 1u);          // round-to-nearest-even
  return (unsigned short)(u >> 16);
}
static __device__ __forceinline__ float bf2f(unsigned short h) {
  return __uint_as_float(((unsigned int)h) << 16);
}
// HW packed fp32->bf16 (RNE): low short = lo, high short = hi.
static __device__ __forceinline__ unsigned int cvt_pk_bf16(float lo, float hi) {
  unsigned int r;
  asm("v_cvt_pk_bf16_f32 %0, %1, %2" : "=v"(r) : "v"(lo), "v"(hi));
  return r;
}
// LDS bf16x8 fragment load from an 8B-aligned (not 16B) address: 2 x b64.
static __device__ __forceinline__ bf16x8 ldfrag(const unsigned short* p) {
  union { unsigned int u[4]; bf16x8 v; } r;
  uint2 lo = *(const uint2*)p;
  uint2 hi = *(const uint2*)(p + 4);
  r.u[0] = lo.x; r.u[1] = lo.y; r.u[2] = hi.x; r.u[3] = hi.y;
  return r.v;
}

// ---------------------------------------------------------------------------
// prep: Wt[e][c] = bf16(W[c][e]) ; zero rowsum
// ---------------------------------------------------------------------------
__global__ __launch_bounds__(256) void prep_kernel(
    const float* __restrict__ W, unsigned short* __restrict__ Wt,
    float* __restrict__ rowsum) {
  const int e = blockIdx.x, c = threadIdx.x;
  Wt[e * 256 + c] = f2bf(W[c * 256 + e]);
  if (e < 32) rowsum[e * 256 + c] = 0.f;
}

// ---------------------------------------------------------------------------
// Merged feature-map kernel: z<32 -> key path, z>=32 -> query path.
//   P[e][x] = relu(sum_c Wt[e][c] * X[b][c][x])
// key:   phi_k[b][e][n] = P (n-contig) + rowsum[b][e] += sum_n P
// query: phi_q[b][m][e] = P^T / 16 (e-contig)
// 128(e) x 128(x) tile, BK=32.  Deep pipeline:
//  - coalesced float4 X loads + in-reg 4x4 transpose + cvt_pk (6 VMEM/thread/step)
//  - double-buffered LDS (stride 36 shorts), ONE barrier per K-step
//  - two reg sets: issue k+2 early, commit k+1 late (T14)
// ---------------------------------------------------------------------------
__global__ __launch_bounds__(256) void phi_kernel(
    const float* __restrict__ query, const float* __restrict__ key,
    const unsigned short* __restrict__ Wt,
    unsigned short* __restrict__ phi_q, unsigned short* __restrict__ phi_k,
    float* __restrict__ rowsum) {
  __shared__ unsigned short As[2][128 * 36];  // [e][c], stride 36 bf16 = 72 B
  __shared__ unsigned short Bs[2][128 * 36];  // [x][c]
  const int z = blockIdx.z;
  const bool isKey = z < BSZ;
  const int b = z & (BSZ - 1);
  const int x0 = blockIdx.x * 128;
  const int e0 = blockIdx.y * 128;
  const int t = threadIdx.x;
  const int lane = t & 63, wave = t >> 6;
  const int wr = wave >> 1, wc = wave & 1;
  const int q = lane >> 4, l15 = lane & 15;
  const float* Xb = (isKey ? key : query) + (size_t)b * DIMC * NDIM;

  f32x4 acc[4][4];
#pragma unroll
  for (int i = 0; i < 4; ++i)
#pragma unroll
    for (int j = 0; j < 4; ++j) acc[i][j] = (f32x4){0.f, 0.f, 0.f, 0.f};

  // staging coords: X 4x4 block (4 rows c4.., 4 cols n4..); Wt rows arow,+64
  const int n4 = (t & 31) * 4, c4 = (t >> 5) * 4;
  const int arow = t >> 2, ac8 = (t & 3) * 8;
  const float* xsrc = Xb + (size_t)c4 * NDIM + x0 + n4;
  const unsigned short* wtp = Wt + (size_t)(e0 + arow) * 256 + ac8;

  float4 xf0[4], xf1[4];
  uint4 wv0[2], wv1[2];

#define PHI_ISSUE(xf, wv, k0_)                                          \
  do {                                                                  \
    _Pragma("unroll") for (int i = 0; i < 4; ++i)                       \
        xf[i] = *(const float4*)(xsrc + (size_t)((k0_) + i) * NDIM);    \
    wv[0] = *(const uint4*)(wtp + (k0_));                               \
    wv[1] = *(const uint4*)(wtp + 64 * 256 + (k0_));                    \
  } while (0)

#define PHI_COMMIT(xf, wv, bufi)                                        \
  do {                                                                  \
    unsigned short* B_ = &Bs[bufi][0];                                  \
    unsigned short* A_ = &As[bufi][0];                                  \
    const float* fp = (const float*)&xf[0];                             \
    _Pragma("unroll") for (int j = 0; j < 4; ++j) {                     \
      uint2 p;                                                          \
      p.x = cvt_pk_bf16(fp[0 * 4 + j], fp[1 * 4 + j]);                  \
      p.y = cvt_pk_bf16(fp[2 * 4 + j], fp[3 * 4 + j]);                  \
      *(uint2*)&B_[(n4 + j) * 36 + c4] = p;                             \
    }                                                                   \
    *(uint2*)&A_[arow * 36 + ac8] = make_uint2(wv[0].x, wv[0].y);       \
    *(uint2*)&A_[arow * 36 + ac8 + 4] = make_uint2(wv[0].z, wv[0].w);   \
    *(uint2*)&A_[(arow + 64) * 36 + ac8] = make_uint2(wv[1].x, wv[1].y);\
    *(uint2*)&A_[(arow + 64) * 36 + ac8 + 4] =                          \
        make_uint2(wv[1].z, wv[1].w);                                   \
  } while (0)

  // prologue: k=0 and k=1 in flight; commit k=0
  PHI_ISSUE(xf0, wv0, 0);
  PHI_ISSUE(xf1, wv1, 32);
  PHI_COMMIT(xf0, wv0, 0);
  __syncthreads();

#pragma unroll
  for (int it = 0; it < 8; ++it) {
    const int cur = it & 1;
    bf16x8 a[4], bv[4];
#pragma unroll
    for (int i = 0; i < 4; ++i)
      a[i] = ldfrag(&As[cur][(wr * 64 + i * 16 + l15) * 36 + q * 8]);
#pragma unroll
    for (int j = 0; j < 4; ++j)
      bv[j] = ldfrag(&Bs[cur][(wc * 64 + j * 16 + l15) * 36 + q * 8]);
    // issue k=it+2 into the set freed by last iteration's commit
    if (it < 6) {
      if (cur == 0) PHI_ISSUE(xf0, wv0, (it + 2) * 32);
      else          PHI_ISSUE(xf1, wv1, (it + 2) * 32);
    }
#pragma unroll
    for (int i = 0; i < 4; ++i)
#pragma unroll
      for (int j = 0; j < 4; ++j)
        acc[i][j] =
            __builtin_amdgcn_mfma_f32_16x16x32_bf16(a[i], bv[j], acc[i][j], 0, 0, 0);
    // commit k=it+1 (issued one iteration ago) into the other buffer
    if (it < 7) {
      if (cur == 0) PHI_COMMIT(xf1, wv1, 1);
      else          PHI_COMMIT(xf0, wv0, 0);
    }
    __syncthreads();
  }
#undef PHI_ISSUE
#undef PHI_COMMIT

  if (isKey) {
    // phi_k[b][e][n] n-contig + fused rowsum
    unsigned short* dst = phi_k + (size_t)b * DIMC * NDIM;
#pragma unroll
    for (int i = 0; i < 4; ++i)
#pragma unroll
      for (int r = 0; r < 4; ++r) {
        const int e = e0 + wr * 64 + i * 16 + q * 4 + r;
        float s = 0.f;
#pragma unroll
        for (int j = 0; j < 4; ++j) {
          float vv = acc[i][j][r];
          vv = vv > 0.f ? vv : 0.f;
          const int n = x0 + wc * 64 + j * 16 + l15;
          dst[(size_t)e * NDIM + n] = f2bf(vv);
          s += vv;
        }
#pragma unroll
        for (int m = 1; m < 16; m <<= 1) s += __shfl_xor(s, m, 64);
        if (l15 == 0) atomicAdd(&rowsum[b * DIMC + e], s);
      }
  } else {
    // phi_q[b][m][e] e-contig, 4 consecutive e per lane -> 8B stores
    unsigned short* dst = phi_q + (size_t)b * MDIM * DIMC;
#pragma unroll
    for (int i = 0; i < 4; ++i) {
      const int ebase = e0 + wr * 64 + i * 16 + q * 4;
#pragma unroll
      for (int j = 0; j < 4; ++j) {
        const int m = x0 + wc * 64 + j * 16 + l15;
        float r0 = acc[i][j][0], r1 = acc[i][j][1];
        float r2 = acc[i][j][2], r3 = acc[i][j][3];
        r0 = r0 > 0.f ? r0 * 0.0625f : 0.f;
        r1 = r1 > 0.f ? r1 * 0.0625f : 0.f;
        r2 = r2 > 0.f ? r2 * 0.0625f : 0.f;
        r3 = r3 > 0.f ? r3 * 0.0625f : 0.f;
        uint2 p;
        p.x = cvt_pk_bf16(r0, r1);
        p.y = cvt_pk_bf16(r2, r3);
        *(uint2*)&dst[(size_t)m * DIMC + ebase] = p;
      }
    }
  }
}

// ---------------------------------------------------------------------------
// kv partials: kvp[ks][b][d][e] = sum_{n in ks-th chunk} value[b][d][n]*phi_k[b][e][n]
// runtime split-K (1/2/4/8), 128(d) x 128(e) tile, BK=64, bf16 partials.
// ---------------------------------------------------------------------------
__global__ __launch_bounds__(256) void kv_kernel(
    const float* __restrict__ value, const unsigned short* __restrict__ phi_k,
    unsigned short* __restrict__ kvp, int kshift) {
  __shared__ unsigned short As[128 * 72];  // [d][n], stride 72 bf16 = 144 B
  __shared__ unsigned short Bs[128 * 72];  // [e][n]
  const int b = blockIdx.z >> kshift, ks = blockIdx.z & ((1 << kshift) - 1);
  const int d0 = blockIdx.x * 128, e0 = blockIdx.y * 128;
  const int t = threadIdx.x;
  const int lane = t & 63, wave = t >> 6;
  const int wr = wave >> 1, wc = wave & 1;
  const int q = lane >> 4, l15 = lane & 15;
  f32x4 acc[4][4];
#pragma unroll
  for (int i = 0; i < 4; ++i)
#pragma unroll
    for (int j = 0; j < 4; ++j) acc[i][j] = (f32x4){0.f, 0.f, 0.f, 0.f};

  const int row = t >> 2;
  const int c4 = (t & 3) << 2;  // float col base
  const int c8 = (t & 3) << 3;  // short col base

  const float* asrc0 = value + ((size_t)b * DIMC + d0 + row) * NDIM;
  const float* asrc1 = asrc0 + (size_t)64 * NDIM;
  const unsigned short* bsrc0 = phi_k + ((size_t)b * DIMC + e0 + row) * NDIM;
  const unsigned short* bsrc1 = bsrc0 + (size_t)64 * NDIM;

  const int nchunk = NDIM >> kshift;
  const int nbeg = ks * nchunk;
  for (int n0 = nbeg; n0 < nbeg + nchunk; n0 += 64) {
    __syncthreads();
#pragma unroll
    for (int i = 0; i < 4; ++i) {
      float4 f0 = *(const float4*)(asrc0 + n0 + c4 + i * 16);
      float4 f1 = *(const float4*)(asrc1 + n0 + c4 + i * 16);
      uint2 w0, w1;
      w0.x = cvt_pk_bf16(f0.x, f0.y); w0.y = cvt_pk_bf16(f0.z, f0.w);
      w1.x = cvt_pk_bf16(f1.x, f1.y); w1.y = cvt_pk_bf16(f1.z, f1.w);
      *(uint2*)&As[row * 72 + c4 + i * 16] = w0;
      *(uint2*)&As[(row + 64) * 72 + c4 + i * 16] = w1;
    }
#pragma unroll
    for (int i = 0; i < 2; ++i) {
      uint4 p0 = *(const uint4*)(bsrc0 + n0 + c8 + i * 32);
      uint4 p1 = *(const uint4*)(bsrc1 + n0 + c8 + i * 32);
      *(uint4*)&Bs[row * 72 + c8 + i * 32] = p0;
      *(uint4*)&Bs[(row + 64) * 72 + c8 + i * 32] = p1;
    }
    __syncthreads();
#pragma unroll
    for (int kk = 0; kk < 64; kk += 32) {
      bf16x8 a[4], bv[4];
#pragma unroll
      for (int i = 0; i < 4; ++i)
        a[i] = *(const bf16x8*)&As[(wr * 64 + i * 16 + l15) * 72 + kk + q * 8];
#pragma unroll
      for (int j = 0; j < 4; ++j)
        bv[j] = *(const bf16x8*)&Bs[(wc * 64 + j * 16 + l15) * 72 + kk + q * 8];
#pragma unroll
      for (int i = 0; i < 4; ++i)
#pragma unroll
        for (int j = 0; j < 4; ++j)
          acc[i][j] = __builtin_amdgcn_mfma_f32_16x16x32_bf16(a[i], bv[j],
                                                              acc[i][j], 0, 0, 0);
    }
  }
  unsigned short* dst = kvp + (size_t)ks * KVP_STRIDE + (size_t)b * DIMC * DIMC;
#pragma unroll
  for (int i = 0; i < 4; ++i)
#pragma unroll
    for (int j = 0; j < 4; ++j) {
      const int e = e0 + wc * 64 + j * 16 + l15;
#pragma unroll
      for (int r = 0; r < 4; ++r) {
        const int d = d0 + wr * 64 + i * 16 + q * 4 + r;
        dst[(size_t)d * DIMC + e] = f2bf(acc[i][j][r]);
      }
    }
}

// ---------------------------------------------------------------------------
// kvred: kvp[0] = sum over KS bf16 partials (in place into partial 0)
// ---------------------------------------------------------------------------
__global__ __launch_bounds__(256) void kvred_kernel(
    unsigned short* __restrict__ kvp, int KS) {
  const size_t idx8 = ((size_t)blockIdx.x * 256 + threadIdx.x) * 8;
  float s[8];
#pragma unroll
  for (int j = 0; j < 8; ++j) s[j] = 0.f;
  for (int p = 0; p < KS; ++p) {
    uint4 v = *(const uint4*)(kvp + (size_t)p * KVP_STRIDE + idx8);
    const unsigned short* u = (const unsigned short*)&v;
#pragma unroll
    for (int j = 0; j < 8; ++j) s[j] += bf2f(u[j]);
  }
  unsigned int w[4];
#pragma unroll
  for (int j = 0; j < 4; ++j) w[j] = cvt_pk_bf16(s[2 * j], s[2 * j + 1]);
  *(uint4*)(kvp + idx8) = *(const uint4*)w;
}

// ---------------------------------------------------------------------------
// out[b][d][m] = scale[b][m] * sum_e kv[d][e] * phi_q[m][e]   fp32 out
// scale fused: running dot of phi_q rows with LDS-resident rowsum.
// Software-pipelined staging.  No min-waves pin (spill avoidance).
// ---------------------------------------------------------------------------
__global__ __launch_bounds__(256) void out_kernel(
    const unsigned short* __restrict__ kv,
    const unsigned short* __restrict__ phi_q,
    const float* __restrict__ rowsum, float* __restrict__ out) {
  __shared__ unsigned short As[128 * 40];  // [d][e]
  __shared__ unsigned short Bs[128 * 40];  // [m][e]
  __shared__ float rs_lds[256];
  __shared__ float red[512];
  __shared__ float scl[128];
  const int b = blockIdx.z;
  const int m0 = blockIdx.x * 128;
  const int d0 = blockIdx.y * 128;
  const int t = threadIdx.x;
  const int lane = t & 63, wave = t >> 6;
  const int wr = wave >> 1, wc = wave & 1;
  const int q = lane >> 4, l15 = lane & 15;

  rs_lds[t] = rowsum[b * DIMC + t];

  f32x4 acc[4][4];
#pragma unroll
  for (int i = 0; i < 4; ++i)
#pragma unroll
    for (int j = 0; j < 4; ++j) acc[i][j] = (f32x4){0.f, 0.f, 0.f, 0.f};

  const int row = t >> 2, c8 = (t & 3) << 3;
  const unsigned short* a0 = kv + ((size_t)b * DIMC + d0 + row) * DIMC + c8;
  const unsigned short* a1 = a0 + (size_t)64 * DIMC;
  const unsigned short* bsrc0 = phi_q + ((size_t)b * MDIM + m0 + row) * DIMC + c8;
  const unsigned short* bsrc1 = bsrc0 + (size_t)64 * DIMC;
  float sA = 0.f, sB = 0.f;

  // prologue prefetch k0 = 0
  uint4 pa0 = *(const uint4*)a0;
  uint4 pa1 = *(const uint4*)a1;
  uint4 pq0 = *(const uint4*)bsrc0;
  uint4 pq1 = *(const uint4*)bsrc1;

  for (int it = 0; it < 8; ++it) {
    const int k0 = it * 32;
    {
      *(uint4*)&As[row * 40 + c8] = pa0;
      *(uint4*)&As[(row + 64) * 40 + c8] = pa1;
      *(uint4*)&Bs[row * 40 + c8] = pq0;
      *(uint4*)&Bs[(row + 64) * 40 + c8] = pq1;
      const unsigned short* u0 = (const unsigned short*)&pq0;
      const unsigned short* u1 = (const unsigned short*)&pq1;
#pragma unroll
      for (int j = 0; j < 8; ++j) {
        const float r = rs_lds[k0 + c8 + j];
        sA += bf2f(u0[j]) * r;
        sB += bf2f(u1[j]) * r;
      }
    }
    __syncthreads();
    if (it < 7) {
      pa0 = *(const uint4*)(a0 + k0 + 32);
      pa1 = *(const uint4*)(a1 + k0 + 32);
      pq0 = *(const uint4*)(bsrc0 + k0 + 32);
      pq1 = *(const uint4*)(bsrc1 + k0 + 32);
    }
    bf16x8 a[4], bv[4];
#pragma unroll
    for (int i = 0; i < 4; ++i)
      a[i] = *(const bf16x8*)&As[(wr * 64 + i * 16 + l15) * 40 + q * 8];
#pragma unroll
    for (int j = 0; j < 4; ++j)
      bv[j] = *(const bf16x8*)&Bs[(wc * 64 + j * 16 + l15) * 40 + q * 8];
#pragma unroll
    for (int i = 0; i < 4; ++i)
#pragma unroll
      for (int j = 0; j < 4; ++j)
        acc[i][j] =
            __builtin_amdgcn_mfma_f32_16x16x32_bf16(a[i], bv[j], acc[i][j], 0, 0, 0);
    __syncthreads();
  }
  // reduce the 4 per-row scale partials and invert
  red[row * 4 + (t & 3)] = sA;
  red[(row + 64) * 4 + (t & 3)] = sB;
  __syncthreads();
  if (t < 128) {
    float s = red[t * 4] + red[t * 4 + 1] + red[t * 4 + 2] + red[t * 4 + 3];
    scl[t] = 1.f / (s + 1e-8f);
  }
  __syncthreads();

  float* ob = out + (size_t)b * DIMC * MDIM;
#pragma unroll
  for (int j = 0; j < 4; ++j) {
    const int ml = wc * 64 + j * 16 + l15;
    const int m = m0 + ml;
    const float sc = scl[ml];
#pragma unroll
    for (int i = 0; i < 4; ++i) {
#pragma unroll
      for (int r = 0; r < 4; ++r) {
        const int d = d0 + wr * 64 + i * 16 + q * 4 + r;
        ob[(size_t)d * MDIM + m] = acc[i][j][r] * sc;
      }
    }
  }
}

extern "C" void kernel_launch(void* const* d_in, const int* in_sizes, int n_in,
                              void* d_out, int out_size, void* d_ws, size_t ws_size,
                              hipStream_t stream) {
  const float* query = (const float*)d_in[0];  // [B,256,M]
  const float* key   = (const float*)d_in[1];  // [B,256,N]
  const float* value = (const float*)d_in[2];  // [B,256,N]
  const float* W     = (const float*)d_in[3];  // [256,256]
  float* out = (float*)d_out;                  // [B,256,M]

  unsigned short* Wt    = (unsigned short*)d_ws;             // 256*256
  unsigned short* phi_q = Wt + 65536;                        // B*M*256 (m-major)
  unsigned short* phi_k = phi_q + (size_t)BSZ * MDIM * DIMC; // B*256*N (e-major)
  unsigned short* kvp   = phi_k + (size_t)BSZ * DIMC * NDIM; // KS * B*256*256 bf16

  // choose split-K factor to fit the workspace (8 -> 4 -> 2 -> 1)
  const size_t base_shorts =
      65536 + (size_t)BSZ * MDIM * DIMC + (size_t)BSZ * DIMC * NDIM;
  int KS = 8, kshift = 3;
  while (KS > 1 &&
         (base_shorts + (size_t)KS * KVP_STRIDE) * 2 + (size_t)BSZ * DIMC * 4 >
             ws_size) {
    KS >>= 1;
    kshift -= 1;
  }
  float* rowsum = (float*)(kvp + (size_t)KS * KVP_STRIDE);   // B*256

  hipLaunchKernelGGL(prep_kernel, dim3(256), dim3(256), 0, stream, W, Wt, rowsum);
  hipLaunchKernelGGL(phi_kernel, dim3(MDIM / 128, DIMC / 128, BSZ * 2),
                     dim3(256), 0, stream, query, key, Wt, phi_q, phi_k, rowsum);
  hipLaunchKernelGGL(kv_kernel, dim3(DIMC / 128, DIMC / 128, BSZ << kshift),
                     dim3(256), 0, stream, value, phi_k, kvp, kshift);
  if (KS > 1)
    hipLaunchKernelGGL(kvred_kernel, dim3(1024), dim3(256), 0, stream, kvp, KS);
  hipLaunchKernelGGL(out_kernel, dim3(MDIM / 128, DIMC / 128, BSZ), dim3(256),
                     0, stream, kvp, phi_q, rowsum, out);
}